// Round 9
// baseline (328.791 us; speedup 1.0000x reference)
//
#include <hip/hip_runtime.h>

#define NN 50000
#define NE 800000
#define IN_C 256
#define HID_C 256
#define OUT_C 128

#define NET (NE + NN)  // csr entries incl one self-loop per node
#define NBUCK 196   // ceil(NN/256) buckets of 256 nodes (by col)
#define CHUNK 4096  // edges per pass-A block
#define NPA 196     // ceil(NE/CHUNK)
#define CAP_B 5120  // pass-B LDS capacity (bucket mean 4096+256 self, sigma ~64)
#define NGRP (NN / 16)  // 3125 16-node groups

typedef unsigned short u16;
typedef unsigned int u32;
typedef __attribute__((ext_vector_type(8))) short short8;
typedef __attribute__((ext_vector_type(4))) short short4_t;
typedef __attribute__((ext_vector_type(8))) unsigned short ushort8;
typedef __attribute__((ext_vector_type(4))) float f32x4;
typedef __attribute__((ext_vector_type(4))) unsigned u32x4;
typedef __attribute__((ext_vector_type(4), aligned(4))) unsigned u32x4u;  // dword-aligned vec load

// planar plane stride (u16 units): 32 ch x (NN+1) rows, zero row at index NN
#define CPS ((size_t)(NN + 1) * 32)

__device__ __forceinline__ u16 f2b(float f) {
  unsigned int u = __float_as_uint(f);
  return (u16)((u + 0x7FFFu + ((u >> 16) & 1u)) >> 16);  // RNE
}
__device__ __forceinline__ float b2f(u16 s) {
  return __uint_as_float(((unsigned int)s) << 16);
}

// ---------------- fused: weight convert+transpose, cnt init(=1 self), Hb zero rows ----------------

__global__ __launch_bounds__(256) void convw_zero(const float* __restrict__ W1,
                                                  const float* __restrict__ W2,
                                                  u16* __restrict__ W1t,
                                                  u16* __restrict__ W2t,
                                                  int* __restrict__ cnt,
                                                  u16* __restrict__ Hb,
                                                  int nzb) {
  int b = blockIdx.x;
  if (b < 256) {
    int id = b * 256 + threadIdx.x;
    if (id < 256 * 256) {
      int n = id >> 8, k = id & 255;
      W1t[id] = f2b(W1[k * 256 + n]);
    }
    if (id < 128 * 256) {
      int n = id >> 8, k = id & 255;
      W2t[id] = f2b(W2[k * 128 + n]);
    }
  } else if (b < 256 + nzb) {
    int i = (b - 256) * 256 + threadIdx.x;
    if (i < NN) cnt[i] = 1;  // self-loop included in CSR now
  } else {
    // zero row at tail of each of the 8 Hb planes (absorbs clamped tail slots)
    int t = threadIdx.x;  // 256 threads = 8 planes x 32 ch
    Hb[(size_t)(t >> 5) * CPS + (size_t)NN * 32 + (t & 31)] = 0;
  }
}

// ---------------- CSR build ----------------

__global__ __launch_bounds__(256) void hist_kernel(const int* __restrict__ col,
                                                   int* __restrict__ cnt, int E) {
  int e = blockIdx.x * blockDim.x + threadIdx.x;
  if (e < E) atomicAdd(&cnt[col[e]], 1);
}

__global__ __launch_bounds__(256) void scan1_kernel(const int* __restrict__ cnt,
                                                    int* __restrict__ bsum, int n) {
  __shared__ int ws[4];
  int i = blockIdx.x * 256 + threadIdx.x;
  int lane = threadIdx.x & 63, wid = threadIdx.x >> 6;
  int v = (i < n) ? cnt[i] : 0;
#pragma unroll
  for (int off = 32; off > 0; off >>= 1) v += __shfl_down(v, off, 64);
  if (lane == 0) ws[wid] = v;
  __syncthreads();
  if (threadIdx.x == 0) bsum[blockIdx.x] = ws[0] + ws[1] + ws[2] + ws[3];
}

__global__ __launch_bounds__(256) void scan2_kernel(const int* __restrict__ bsum,
                                                    int* __restrict__ boff,
                                                    int* __restrict__ row_off,
                                                    int nb, int n) {
  __shared__ int wsum[4], wpre[5];
  int lane = threadIdx.x & 63, wid = threadIdx.x >> 6;
  int v = (threadIdx.x < nb) ? bsum[threadIdx.x] : 0;
  int s = v;
#pragma unroll
  for (int off = 1; off < 64; off <<= 1) {
    int t = __shfl_up(s, off, 64);
    if (lane >= off) s += t;
  }
  if (lane == 63) wsum[wid] = s;
  __syncthreads();
  if (threadIdx.x == 0) {
    int acc = 0;
#pragma unroll
    for (int w = 0; w < 4; ++w) { wpre[w] = acc; acc += wsum[w]; }
    wpre[4] = acc;
  }
  __syncthreads();
  if (threadIdx.x < nb) boff[threadIdx.x] = wpre[wid] + (s - v);
  if (threadIdx.x == 0) row_off[n] = wpre[4];
}

// scan3 also seeds per-bucket stage cursors (bcur[b] = row_off[b*256])
__global__ __launch_bounds__(256) void scan3_kernel(const int* __restrict__ cnt,
                                                    const int* __restrict__ boff,
                                                    int* __restrict__ row_off,
                                                    int* __restrict__ bcur,
                                                    float* __restrict__ dinv, int n) {
  __shared__ int wsum[4], wpre[4];
  int i = blockIdx.x * 256 + threadIdx.x;
  int lane = threadIdx.x & 63, wid = threadIdx.x >> 6;
  int v = (i < n) ? cnt[i] : 0;
  int s = v;
#pragma unroll
  for (int off = 1; off < 64; off <<= 1) {
    int t = __shfl_up(s, off, 64);
    if (lane >= off) s += t;
  }
  if (lane == 63) wsum[wid] = s;
  __syncthreads();
  if (threadIdx.x == 0) {
    int acc = 0;
#pragma unroll
    for (int w = 0; w < 4; ++w) { wpre[w] = acc; acc += wsum[w]; }
  }
  __syncthreads();
  if (i < n) {
    int off = boff[blockIdx.x] + wpre[wid] + (s - v);
    row_off[i] = off;
    if ((i & 255) == 0) bcur[i >> 8] = off;
    dinv[i] = rsqrtf((float)v);  // v = deg+1 (cnt seeded at 1)
  }
}

// ---------------- MFMA GEMM body (shared by plain and fused kernels) ----------------
// PLANAR_C: C write remapped to [gc>>5][gr][gc&31] planes of stride CPS.

template <bool A_IS_F32, bool PLANAR_C>
__device__ __forceinline__ void gemm_body(const void* __restrict__ Ap,
                                          const u16* __restrict__ Bt,
                                          const float* __restrict__ dscale,
                                          u16* __restrict__ C, int M, int N,
                                          int bx, int by,
                                          u16 (&Asl)[2][5120], u16 (&Bsl)[2][5120]) {
  const int tid = threadIdx.x;
  const int row0 = by * 128;
  const int col0 = bx * 128;

  f32x4 acc[4][4] = {};

  const int seg = tid & 7;
  const int rb = tid >> 3;
  const int wave = tid >> 6, lane = tid & 63;
  const int wm = wave >> 1, wn = wave & 1;
  const int qr = lane & 15, quad = lane >> 4;

  float4 aF[4];
  ushort4 aU[4];
  ushort4 bR[4];

  auto load_tiles = [&](int k0) {
    if constexpr (A_IS_F32) {
      const float* A = (const float*)Ap;
#pragma unroll
      for (int i = 0; i < 4; ++i) {
        int gr = row0 + rb + i * 32;
        aF[i] = (gr < M) ? *(const float4*)&A[(size_t)gr * 256 + k0 + seg * 4]
                         : make_float4(0.f, 0.f, 0.f, 0.f);
      }
    } else {
      const u16* A = (const u16*)Ap;
#pragma unroll
      for (int i = 0; i < 4; ++i) {
        int gr = row0 + rb + i * 32;
        aU[i] = (gr < M) ? *(const ushort4*)&A[(size_t)gr * 256 + k0 + seg * 4]
                         : make_ushort4(0, 0, 0, 0);
      }
    }
#pragma unroll
    for (int i = 0; i < 4; ++i) {
      int n = rb + i * 32;
      bR[i] = *(const ushort4*)&Bt[(size_t)(col0 + n) * 256 + k0 + seg * 4];
    }
  };

  auto write_lds = [&](int buf) {
#pragma unroll
    for (int i = 0; i < 4; ++i) {
      int r = rb + i * 32;
      ushort4 u;
      if constexpr (A_IS_F32) {
        u.x = f2b(aF[i].x); u.y = f2b(aF[i].y);
        u.z = f2b(aF[i].z); u.w = f2b(aF[i].w);
      } else {
        u = aU[i];
      }
      *(ushort4*)&Asl[buf][r * 40 + seg * 4] = u;
      *(ushort4*)&Bsl[buf][r * 40 + seg * 4] = bR[i];
    }
  };

  load_tiles(0);
  write_lds(0);
  __syncthreads();

#pragma unroll
  for (int it = 0; it < 8; ++it) {
    const int cur = it & 1;
    if (it < 7) load_tiles((it + 1) * 32);

    short8 afr[4], bfr[4];
#pragma unroll
    for (int mt = 0; mt < 4; ++mt)
      afr[mt] = *(const short8*)&Asl[cur][(wm * 64 + mt * 16 + qr) * 40 + quad * 8];
#pragma unroll
    for (int nt = 0; nt < 4; ++nt)
      bfr[nt] = *(const short8*)&Bsl[cur][(wn * 64 + nt * 16 + qr) * 40 + quad * 8];
#pragma unroll
    for (int mt = 0; mt < 4; ++mt)
#pragma unroll
      for (int nt = 0; nt < 4; ++nt)
        acc[mt][nt] = __builtin_amdgcn_mfma_f32_16x16x32_bf16(afr[mt], bfr[nt], acc[mt][nt], 0, 0, 0);

    if (it < 7) {
      write_lds(1 - cur);
      __syncthreads();
    }
  }

#pragma unroll
  for (int mt = 0; mt < 4; ++mt) {
#pragma unroll
    for (int i = 0; i < 4; ++i) {
      int gr = row0 + wm * 64 + mt * 16 + quad * 4 + i;
      if (gr < M) {
        float sc = dscale[gr];
#pragma unroll
        for (int nt = 0; nt < 4; ++nt) {
          int gc = col0 + wn * 64 + nt * 16 + qr;
          u16 val = f2b(acc[mt][nt][i] * sc);
          if constexpr (PLANAR_C)
            C[(size_t)(gc >> 5) * CPS + (size_t)gr * 32 + (gc & 31)] = val;
          else
            C[(size_t)gr * N + gc] = val;
        }
      }
    }
  }
}

// plain GEMM kernel (layer 2): planar C out; block (0,0) seeds the 4 H3 plane
// zero rows (must happen after csr_sort consumed the stage overlay).
template <bool A_IS_F32, bool PLANAR_C>
__global__ __launch_bounds__(256) void gemm_mfma(const void* __restrict__ Ap,
                                                 const u16* __restrict__ Bt,
                                                 const float* __restrict__ dscale,
                                                 u16* __restrict__ C, int M, int N,
                                                 u16* __restrict__ zrow) {
  if (zrow != nullptr && blockIdx.x == 0 && blockIdx.y == 0 && threadIdx.x < 128) {
    int t = threadIdx.x;  // 4 planes x 32 ch
    zrow[(size_t)(t >> 5) * CPS + (size_t)NN * 32 + (t & 31)] = 0;
  }
  __shared__ u16 Asl[2][5120];
  __shared__ u16 Bsl[2][5120];
  gemm_body<A_IS_F32, PLANAR_C>(Ap, Bt, dscale, C, M, N, blockIdx.x, blockIdx.y, Asl, Bsl);
}

// fused: GEMM1 (blocks [0,ngb), planar Hb out) + pass-A bucket scatter
__global__ __launch_bounds__(256) void gemm1_scatter(const float* __restrict__ x,
                                                     const u16* __restrict__ W1t,
                                                     const float* __restrict__ dinv,
                                                     u16* __restrict__ Hb, int M, int N,
                                                     int ngb,
                                                     const int* __restrict__ row,
                                                     const int* __restrict__ col,
                                                     int* __restrict__ bcur,
                                                     uint2* __restrict__ stage, int E) {
  __shared__ u16 ABsl[4][5120];  // 40KB: GEMM A/B double-buffer OR pass-A staging
  int b = blockIdx.x;
  if (b < ngb) {
    gemm_body<true, true>(x, W1t, dinv, Hb, M, N, b & 1, b >> 1,
                          *reinterpret_cast<u16(*)[2][5120]>(&ABsl[0]),
                          *reinterpret_cast<u16(*)[2][5120]>(&ABsl[2]));
  } else {
    uint2* pairs = (uint2*)ABsl;                       // 4096 pairs = 32KB
    int* hcnt = (int*)((char*)ABsl + 32768);           // [256]
    int* hscan = hcnt + 256;                           // [256]
    int* hbase = hscan + 256;                          // [256]
    int* lcur = hbase + 256;                           // [256]

    const int tid = threadIdx.x;
    const int blk = b - ngb;
    const int e0 = blk * CHUNK;

    hcnt[tid] = 0;
    __syncthreads();

    int ecol[16], erow[16];
#pragma unroll
    for (int j = 0; j < 16; ++j) {
      int e = e0 + j * 256 + tid;
      if (e < E) {
        ecol[j] = col[e];
        erow[j] = row[e];
        atomicAdd(&hcnt[ecol[j] >> 8], 1);
      } else {
        ecol[j] = -1;
      }
    }
    __syncthreads();

    hscan[tid] = hcnt[tid];
    __syncthreads();
#pragma unroll
    for (int off = 1; off < 256; off <<= 1) {
      int t = (tid >= off) ? hscan[tid - off] : 0;
      __syncthreads();
      hscan[tid] += t;
      __syncthreads();
    }

    lcur[tid] = 0;
    if (hcnt[tid] > 0) hbase[tid] = atomicAdd(&bcur[tid], hcnt[tid]);
    __syncthreads();

#pragma unroll
    for (int j = 0; j < 16; ++j) {
      if (ecol[j] >= 0) {
        int bk = ecol[j] >> 8;
        int p = atomicAdd(&lcur[bk], 1);
        pairs[(hscan[bk] - hcnt[bk]) + p] = make_uint2((unsigned)erow[j], (unsigned)ecol[j]);
      }
    }
    __syncthreads();

    int mtot = hscan[255];
    for (int s = tid; s < mtot; s += 256) {
      uint2 pr = pairs[s];
      int bk = (int)(pr.y >> 8);
      stage[hbase[bk] + (s - (hscan[bk] - hcnt[bk]))] = pr;
    }
  }
}

// pass B: per-bucket counting-sort to exact csr positions, inserting one
// self-loop per node FIRST in its range. Output packed: low16 = src row index
// (NN+1 <= 2^16), high16 = owner = node&15 (local index within its 16-group).
__global__ __launch_bounds__(256) void csr_sort(const uint2* __restrict__ stage,
                                                const int* __restrict__ row_off,
                                                u32* __restrict__ csrp) {
  __shared__ int cur[256];
  __shared__ u32 outb[CAP_B];
  const int b = blockIdx.x;
  const int base_node = b << 8;
  const int nnodes = min(256, NN - base_node);
  const int tid = threadIdx.x;
  const int bstart = row_off[base_node];
  const int bend = row_off[min(base_node + 256, NN)];
  if (tid < nnodes) {
    int c0 = row_off[base_node + tid] - bstart;
    outb[c0] = (u32)(base_node + tid) | ((u32)(tid & 15) << 16);  // self-loop
    cur[tid] = c0 + 1;
  }
  __syncthreads();
  const int m = bend - bstart;
  const int mreal = m - nnodes;  // staged (real) edges in this bucket
  for (int i = tid; i < mreal; i += 256) {
    uint2 pr = stage[bstart + i];
    int cl = ((int)pr.y - base_node) & 255;  // defensive
    int p = atomicAdd(&cur[cl], 1);
    u32 val = (pr.x & 0xFFFFu) | ((u32)(cl & 15) << 16);
    if (p < CAP_B) outb[p] = val;
    else if (bstart + p < NET) csrp[bstart + p] = val;  // bounded fallback
  }
  __syncthreads();
  const int mm = min(m, CAP_B);
  for (int i = tid; i < mm; i += 256) csrp[bstart + i] = outb[i];
}

// ---------------- aggregation: SpMM via indicator-MFMA, software-pipelined ----------------
// Datapath identical to the verified r8 kernel (indicator A from owner ids,
// B staged 32 rows x 32 ch to wave-private LDS, read back via
// ds_read_b64_tr_b16, 2 MFMAs per K-step, tail clamped to plane zero row).
// NEW (r8 was serial-latency-bound at T_iter~3000cy with all pipes <30%):
//  - csrp (src word + owner words) prefetched 3 K-steps ahead in rotating
//    named registers (static indexing), loaded NONTEMPORAL so the streamed
//    csrp does not evict this XCD's 3.2MB plane from its 4MB L2.
//  - gather issued 1 K-step ahead into registers; the ds_write then waits on
//    a load issued a full iteration earlier.
//  - all global loads precede the asm block; asm waits lgkmcnt only.
// Steady-state chain: ds_write -> lgkmcnt -> tr-read -> MFMA (~300cy).
template <int NPL, int OUTC, bool RELU_BF16>
__global__ __launch_bounds__(256) void agg_mfma(const u16* __restrict__ h,
                                                const int* __restrict__ row_off,
                                                const u32* __restrict__ csrp,
                                                const float* __restrict__ dinv,
                                                const float* __restrict__ bias,
                                                void* __restrict__ outp) {
  __shared__ char lds[4][2048];
  const int slice = blockIdx.x % NPL;
  const int wave = threadIdx.x >> 6;
  const int g = (blockIdx.x / NPL) * 4 + wave;
  if (g >= NGRP) return;
  const int lane = threadIdx.x & 63;
  const int qr = lane & 15, quad = lane >> 4;
  const int s = lane >> 1, half = lane & 1;  // staging role: slot s, ch-half
  const u16* hpl = h + (size_t)slice * CPS;
  const int beg = row_off[g * 16];
  const int end = row_off[g * 16 + 16];
  const int nsteps = (end - beg + 31) >> 5;
  char* wl = lds[wave];
  char* wp = wl + (half * 1024 + ((s >> 2) & 1) * 512 + (s >> 3) * 128 + (s & 3) * 32);
  const unsigned trb = (unsigned)(size_t)(wl) + (unsigned)(lane * 8);

  // csrp loads (nontemporal; reads up to 3 steps past end stay within the
  // +256-dword slack of the csrp allocation; values clamped at use)
  auto ldC = [&](int t, u32& cw, u32x4u& w0, u32x4u& w1) {
    int base = beg + t * 32;
    cw = __builtin_nontemporal_load(&csrp[base + s]);
    w0 = __builtin_nontemporal_load((const u32x4u*)&csrp[base + quad * 8]);
    w1 = __builtin_nontemporal_load((const u32x4u*)&csrp[base + quad * 8 + 4]);
  };
  auto ldG = [&](int t, u32 cw, u32x4& d0, u32x4& d1) {
    int p = beg + t * 32 + s;
    unsigned src = (p < end) ? (cw & 0xFFFFu) : (unsigned)NN;  // tail -> zero row
    const u16* rp = hpl + (size_t)src * 32 + half * 16;
    d0 = *(const u32x4*)rp;
    d1 = *(const u32x4*)(rp + 8);
  };

  // pipeline registers: stage k holds csrp data for step t+k (k=0,1,2)
  u32 cw0, cw1, cw2;
  u32x4u w0a, w1a, w0b, w1b, w0c, w1c;
  ldC(0, cw0, w0a, w1a);
  ldC(1, cw1, w0b, w1b);
  ldC(2, cw2, w0c, w1c);
  u32x4 gd0, gd1, nd0, nd1;
  ldG(0, cw0, gd0, gd1);

  f32x4 acc0 = {}, acc1 = {};
  for (int t = 0; t < nsteps; ++t) {
    u32 cw3;
    u32x4u w0n, w1n;
    ldC(t + 3, cw3, w0n, w1n);                 // csrp 3 ahead
    if (t + 1 < nsteps) ldG(t + 1, cw1, nd0, nd1);  // gather 1 ahead (uniform branch)
    *(u32x4*)wp = gd0;                          // stage current (vmcnt wait: 1-iter-old load)
    *(u32x4*)(wp + 16) = gd1;
    short4_t t00, t01, t10, t11;
    asm volatile("s_waitcnt lgkmcnt(0)\n\t"
                 "ds_read_b64_tr_b16 %0, %4 offset:0\n\t"
                 "ds_read_b64_tr_b16 %1, %4 offset:512\n\t"
                 "ds_read_b64_tr_b16 %2, %4 offset:1024\n\t"
                 "ds_read_b64_tr_b16 %3, %4 offset:1536\n\t"
                 "s_waitcnt lgkmcnt(0)"
                 : "=&v"(t00), "=&v"(t01), "=&v"(t10), "=&v"(t11)
                 : "v"(trb)
                 : "memory");
    __builtin_amdgcn_sched_barrier(0);  // keep MFMA below the lgkmcnt (hipcc hoists otherwise)
    short8 afr;
#pragma unroll
    for (int j = 0; j < 4; ++j) {
      afr[j]     = (short)(((w0a[j] >> 16) == (unsigned)qr) ? 0x3F80 : 0);
      afr[j + 4] = (short)(((w1a[j] >> 16) == (unsigned)qr) ? 0x3F80 : 0);
    }
    short8 b0 = __builtin_shufflevector(t00, t01, 0, 1, 2, 3, 4, 5, 6, 7);
    short8 b1 = __builtin_shufflevector(t10, t11, 0, 1, 2, 3, 4, 5, 6, 7);
    acc0 = __builtin_amdgcn_mfma_f32_16x16x32_bf16(afr, b0, acc0, 0, 0, 0);
    acc1 = __builtin_amdgcn_mfma_f32_16x16x32_bf16(afr, b1, acc1, 0, 0, 0);
    // rotate pipeline registers (SSA copies; compiler folds via unroll)
    cw0 = cw1; w0a = w0b; w1a = w1b;
    cw1 = cw2; w0b = w0c; w1b = w1c;
    cw2 = cw3; w0c = w0n; w1c = w1n;
    gd0 = nd0; gd1 = nd1;
  }
  // epilogue: C mapping col=lane&15 (ch), row=(lane>>4)*4+i (node)
  const int node0 = g * 16 + quad * 4;
  const int chb = slice * 32;
  float bv0 = bias[chb + qr];
  float bv1 = bias[chb + 16 + qr];
#pragma unroll
  for (int i = 0; i < 4; ++i) {
    float dv = dinv[node0 + i];
    float r0 = acc0[i] * dv + bv0;
    float r1 = acc1[i] * dv + bv1;
    if constexpr (RELU_BF16) {
      u16* o = (u16*)outp;
      o[(size_t)(node0 + i) * OUTC + chb + qr] = f2b(fmaxf(r0, 0.f));
      o[(size_t)(node0 + i) * OUTC + chb + 16 + qr] = f2b(fmaxf(r1, 0.f));
    } else {
      float* o = (float*)outp;
      o[(size_t)(node0 + i) * OUTC + chb + qr] = r0;
      o[(size_t)(node0 + i) * OUTC + chb + 16 + qr] = r1;
    }
  }
}

// ---------------- launch ----------------

extern "C" void kernel_launch(void* const* d_in, const int* in_sizes, int n_in,
                              void* d_out, int out_size, void* d_ws, size_t ws_size,
                              hipStream_t stream) {
  const float* x = (const float*)d_in[0];
  const int* ei = (const int*)d_in[1];
  const float* W1 = (const float*)d_in[2];
  const float* b1 = (const float*)d_in[3];
  const float* W2 = (const float*)d_in[4];
  const float* b2 = (const float*)d_in[5];
  float* out = (float*)d_out;

  const int* row = ei;
  const int* col = ei + NE;

  const int NB = (NN + 255) / 256;  // 196

  // workspace layout — Hb: 8 planar planes [(NN+1)x32]; H3b: 4 planar planes.
  u16* Hb = (u16*)d_ws;                       // 8*CPS bf16, pre-scaled by dinv[row]
  u16* H2b = Hb + (size_t)(NN + 1) * 256;     // [NN,256] bf16 (standard layout)
  u16* H3b = H2b + (size_t)NN * 256;          // 4*CPS bf16, pre-scaled
  u16* W1t = H3b + (size_t)(NN + 1) * 128;    // [256,256] bf16
  u16* W2t = W1t + 256 * 256;                 // [128,256] bf16
  int* cnt = (int*)(W2t + 128 * 256);         // [NN]
  int* row_off = cnt + NN;                    // [NN+4] (padded)
  int* bcur = row_off + NN + 4;               // [256] per-bucket stage cursors
  float* dinv = (float*)(bcur + 256);         // [NN]
  int* bsum = (int*)(dinv + NN);              // [200]
  int* boff = bsum + 200;                     // [200]
  u32* csrp = (u32*)(boff + 200);             // [NET+256] packed src|own<<16 (+slack for 3-deep prefetch)
  // stage overlays H3b (disjoint lifetimes); H3 zero rows re-seeded in gemm2.
  uint2* stage = (uint2*)H3b;                 // [NE] (row,col) pairs

  convw_zero<<<256 + NB + 1, 256, 0, stream>>>(W1, W2, W1t, W2t, cnt, Hb, NB);
  hist_kernel<<<(NE + 255) / 256, 256, 0, stream>>>(col, cnt, NE);
  scan1_kernel<<<NB, 256, 0, stream>>>(cnt, bsum, NN);
  scan2_kernel<<<1, 256, 0, stream>>>(bsum, boff, row_off, NB, NN);
  scan3_kernel<<<NB, 256, 0, stream>>>(cnt, boff, row_off, bcur, dinv, NN);

  // fused: GEMM1 (planar Hb = dinv * (x@W1), bf16) concurrent with pass-A scatter
  {
    const int ngb = (HID_C / 128) * ((NN + 127) / 128);  // 782
    gemm1_scatter<<<ngb + NPA, 256, 0, stream>>>(x, W1t, dinv, Hb, NN, HID_C, ngb,
                                                 row, col, bcur, stage, NE);
  }
  csr_sort<<<NBUCK, 256, 0, stream>>>(stage, row_off, csrp);

  const int NG4 = (NGRP + 3) / 4;  // 782 blocks of 4 groups
  // agg1: 8 planes x 32 ch, plane==XCD via blockIdx%8
  agg_mfma<8, 256, true><<<NG4 * 8, 256, 0, stream>>>(
      Hb, row_off, csrp, dinv, b1, H2b);

  {
    dim3 grid(OUT_C / 128, (NN + 127) / 128);
    gemm_mfma<false, true><<<grid, 256, 0, stream>>>(H2b, W2t, dinv, H3b, NN, OUT_C, H3b);
  }

  // agg2: 4 planes x 32 ch
  agg_mfma<4, 128, false><<<NG4 * 4, 256, 0, stream>>>(
      H3b, row_off, csrp, dinv, b2, out);
}

// Round 10
// 268.147 us; speedup vs baseline: 1.2262x; 1.2262x over previous
//
#include <hip/hip_runtime.h>

#define NN 50000
#define NE 800000
#define IN_C 256
#define HID_C 256
#define OUT_C 128

#define NET (NE + NN)  // csr entries incl one self-loop per node
#define NBUCK 196   // ceil(NN/256) buckets of 256 nodes (by col)
#define CHUNK 4096  // edges per pass-A block
#define NPA 196     // ceil(NE/CHUNK)
#define CAP_B 5120  // pass-B LDS capacity (bucket mean 4096+256 self, sigma ~64)

typedef unsigned short u16;
typedef unsigned int u32;
typedef __attribute__((ext_vector_type(8))) short short8;
typedef __attribute__((ext_vector_type(8))) unsigned short ushort8;
typedef __attribute__((ext_vector_type(4))) float f32x4;
typedef __attribute__((ext_vector_type(2))) float f32x2;
typedef __attribute__((ext_vector_type(4))) unsigned u32x4;
typedef __attribute__((ext_vector_type(4), aligned(4))) unsigned u32x4u;  // dword-aligned vec load (HW-verified r8/r9)

// planar plane stride (u16 units): 32 ch x (NN+1) rows, zero row at index NN
#define CPS ((size_t)(NN + 1) * 32)

__device__ __forceinline__ u16 f2b(float f) {
  unsigned int u = __float_as_uint(f);
  return (u16)((u + 0x7FFFu + ((u >> 16) & 1u)) >> 16);  // RNE
}
__device__ __forceinline__ float b2f(u16 s) {
  return __uint_as_float(((unsigned int)s) << 16);
}

// ---------------- fused: weight convert+transpose, cnt init(=1 self), Hb zero rows ----------------

__global__ __launch_bounds__(256) void convw_zero(const float* __restrict__ W1,
                                                  const float* __restrict__ W2,
                                                  u16* __restrict__ W1t,
                                                  u16* __restrict__ W2t,
                                                  int* __restrict__ cnt,
                                                  u16* __restrict__ Hb,
                                                  int nzb) {
  int b = blockIdx.x;
  if (b < 256) {
    int id = b * 256 + threadIdx.x;
    if (id < 256 * 256) {
      int n = id >> 8, k = id & 255;
      W1t[id] = f2b(W1[k * 256 + n]);
    }
    if (id < 128 * 256) {
      int n = id >> 8, k = id & 255;
      W2t[id] = f2b(W2[k * 128 + n]);
    }
  } else if (b < 256 + nzb) {
    int i = (b - 256) * 256 + threadIdx.x;
    if (i < NN) cnt[i] = 1;  // self-loop included in CSR
  } else {
    // zero row at tail of each of the 8 Hb planes (absorbs clamped tail slots)
    int t = threadIdx.x;  // 256 threads = 8 planes x 32 ch
    Hb[(size_t)(t >> 5) * CPS + (size_t)NN * 32 + (t & 31)] = 0;
  }
}

// ---------------- CSR build ----------------

__global__ __launch_bounds__(256) void hist_kernel(const int* __restrict__ col,
                                                   int* __restrict__ cnt, int E) {
  int e = blockIdx.x * blockDim.x + threadIdx.x;
  if (e < E) atomicAdd(&cnt[col[e]], 1);
}

__global__ __launch_bounds__(256) void scan1_kernel(const int* __restrict__ cnt,
                                                    int* __restrict__ bsum, int n) {
  __shared__ int ws[4];
  int i = blockIdx.x * 256 + threadIdx.x;
  int lane = threadIdx.x & 63, wid = threadIdx.x >> 6;
  int v = (i < n) ? cnt[i] : 0;
#pragma unroll
  for (int off = 32; off > 0; off >>= 1) v += __shfl_down(v, off, 64);
  if (lane == 0) ws[wid] = v;
  __syncthreads();
  if (threadIdx.x == 0) bsum[blockIdx.x] = ws[0] + ws[1] + ws[2] + ws[3];
}

__global__ __launch_bounds__(256) void scan2_kernel(const int* __restrict__ bsum,
                                                    int* __restrict__ boff,
                                                    int* __restrict__ row_off,
                                                    int nb, int n) {
  __shared__ int wsum[4], wpre[5];
  int lane = threadIdx.x & 63, wid = threadIdx.x >> 6;
  int v = (threadIdx.x < nb) ? bsum[threadIdx.x] : 0;
  int s = v;
#pragma unroll
  for (int off = 1; off < 64; off <<= 1) {
    int t = __shfl_up(s, off, 64);
    if (lane >= off) s += t;
  }
  if (lane == 63) wsum[wid] = s;
  __syncthreads();
  if (threadIdx.x == 0) {
    int acc = 0;
#pragma unroll
    for (int w = 0; w < 4; ++w) { wpre[w] = acc; acc += wsum[w]; }
    wpre[4] = acc;
  }
  __syncthreads();
  if (threadIdx.x < nb) boff[threadIdx.x] = wpre[wid] + (s - v);
  if (threadIdx.x == 0) row_off[n] = wpre[4];
}

// scan3 also seeds per-bucket stage cursors (bcur[b] = row_off[b*256])
__global__ __launch_bounds__(256) void scan3_kernel(const int* __restrict__ cnt,
                                                    const int* __restrict__ boff,
                                                    int* __restrict__ row_off,
                                                    int* __restrict__ bcur,
                                                    float* __restrict__ dinv, int n) {
  __shared__ int wsum[4], wpre[4];
  int i = blockIdx.x * 256 + threadIdx.x;
  int lane = threadIdx.x & 63, wid = threadIdx.x >> 6;
  int v = (i < n) ? cnt[i] : 0;
  int s = v;
#pragma unroll
  for (int off = 1; off < 64; off <<= 1) {
    int t = __shfl_up(s, off, 64);
    if (lane >= off) s += t;
  }
  if (lane == 63) wsum[wid] = s;
  __syncthreads();
  if (threadIdx.x == 0) {
    int acc = 0;
#pragma unroll
    for (int w = 0; w < 4; ++w) { wpre[w] = acc; acc += wsum[w]; }
  }
  __syncthreads();
  if (i < n) {
    int off = boff[blockIdx.x] + wpre[wid] + (s - v);
    row_off[i] = off;
    if ((i & 255) == 0) bcur[i >> 8] = off;
    dinv[i] = rsqrtf((float)v);  // v = deg+1 (cnt seeded at 1)
  }
}

// ---------------- MFMA GEMM body (shared by plain and fused kernels) ----------------
// PLANAR_C: C write remapped to [gc>>5][gr][gc&31] planes of stride CPS.

template <bool A_IS_F32, bool PLANAR_C>
__device__ __forceinline__ void gemm_body(const void* __restrict__ Ap,
                                          const u16* __restrict__ Bt,
                                          const float* __restrict__ dscale,
                                          u16* __restrict__ C, int M, int N,
                                          int bx, int by,
                                          u16 (&Asl)[2][5120], u16 (&Bsl)[2][5120]) {
  const int tid = threadIdx.x;
  const int row0 = by * 128;
  const int col0 = bx * 128;

  f32x4 acc[4][4] = {};

  const int seg = tid & 7;
  const int rb = tid >> 3;
  const int wave = tid >> 6, lane = tid & 63;
  const int wm = wave >> 1, wn = wave & 1;
  const int qr = lane & 15, quad = lane >> 4;

  float4 aF[4];
  ushort4 aU[4];
  ushort4 bR[4];

  auto load_tiles = [&](int k0) {
    if constexpr (A_IS_F32) {
      const float* A = (const float*)Ap;
#pragma unroll
      for (int i = 0; i < 4; ++i) {
        int gr = row0 + rb + i * 32;
        aF[i] = (gr < M) ? *(const float4*)&A[(size_t)gr * 256 + k0 + seg * 4]
                         : make_float4(0.f, 0.f, 0.f, 0.f);
      }
    } else {
      const u16* A = (const u16*)Ap;
#pragma unroll
      for (int i = 0; i < 4; ++i) {
        int gr = row0 + rb + i * 32;
        aU[i] = (gr < M) ? *(const ushort4*)&A[(size_t)gr * 256 + k0 + seg * 4]
                         : make_ushort4(0, 0, 0, 0);
      }
    }
#pragma unroll
    for (int i = 0; i < 4; ++i) {
      int n = rb + i * 32;
      bR[i] = *(const ushort4*)&Bt[(size_t)(col0 + n) * 256 + k0 + seg * 4];
    }
  };

  auto write_lds = [&](int buf) {
#pragma unroll
    for (int i = 0; i < 4; ++i) {
      int r = rb + i * 32;
      ushort4 u;
      if constexpr (A_IS_F32) {
        u.x = f2b(aF[i].x); u.y = f2b(aF[i].y);
        u.z = f2b(aF[i].z); u.w = f2b(aF[i].w);
      } else {
        u = aU[i];
      }
      *(ushort4*)&Asl[buf][r * 40 + seg * 4] = u;
      *(ushort4*)&Bsl[buf][r * 40 + seg * 4] = bR[i];
    }
  };

  load_tiles(0);
  write_lds(0);
  __syncthreads();

#pragma unroll
  for (int it = 0; it < 8; ++it) {
    const int cur = it & 1;
    if (it < 7) load_tiles((it + 1) * 32);

    short8 afr[4], bfr[4];
#pragma unroll
    for (int mt = 0; mt < 4; ++mt)
      afr[mt] = *(const short8*)&Asl[cur][(wm * 64 + mt * 16 + qr) * 40 + quad * 8];
#pragma unroll
    for (int nt = 0; nt < 4; ++nt)
      bfr[nt] = *(const short8*)&Bsl[cur][(wn * 64 + nt * 16 + qr) * 40 + quad * 8];
#pragma unroll
    for (int mt = 0; mt < 4; ++mt)
#pragma unroll
      for (int nt = 0; nt < 4; ++nt)
        acc[mt][nt] = __builtin_amdgcn_mfma_f32_16x16x32_bf16(afr[mt], bfr[nt], acc[mt][nt], 0, 0, 0);

    if (it < 7) {
      write_lds(1 - cur);
      __syncthreads();
    }
  }

#pragma unroll
  for (int mt = 0; mt < 4; ++mt) {
#pragma unroll
    for (int i = 0; i < 4; ++i) {
      int gr = row0 + wm * 64 + mt * 16 + quad * 4 + i;
      if (gr < M) {
        float sc = dscale[gr];
#pragma unroll
        for (int nt = 0; nt < 4; ++nt) {
          int gc = col0 + wn * 64 + nt * 16 + qr;
          u16 val = f2b(acc[mt][nt][i] * sc);
          if constexpr (PLANAR_C)
            C[(size_t)(gc >> 5) * CPS + (size_t)gr * 32 + (gc & 31)] = val;
          else
            C[(size_t)gr * N + gc] = val;
        }
      }
    }
  }
}

// plain GEMM kernel (layer 2): planar C out; block (0,0) seeds the 4 H3 plane
// zero rows (must happen after csr_sort consumed the stage overlay).
template <bool A_IS_F32, bool PLANAR_C>
__global__ __launch_bounds__(256) void gemm_mfma(const void* __restrict__ Ap,
                                                 const u16* __restrict__ Bt,
                                                 const float* __restrict__ dscale,
                                                 u16* __restrict__ C, int M, int N,
                                                 u16* __restrict__ zrow) {
  if (zrow != nullptr && blockIdx.x == 0 && blockIdx.y == 0 && threadIdx.x < 128) {
    int t = threadIdx.x;  // 4 planes x 32 ch
    zrow[(size_t)(t >> 5) * CPS + (size_t)NN * 32 + (t & 31)] = 0;
  }
  __shared__ u16 Asl[2][5120];
  __shared__ u16 Bsl[2][5120];
  gemm_body<A_IS_F32, PLANAR_C>(Ap, Bt, dscale, C, M, N, blockIdx.x, blockIdx.y, Asl, Bsl);
}

// fused: GEMM1 (blocks [0,ngb), planar Hb out) + pass-A bucket scatter
__global__ __launch_bounds__(256) void gemm1_scatter(const float* __restrict__ x,
                                                     const u16* __restrict__ W1t,
                                                     const float* __restrict__ dinv,
                                                     u16* __restrict__ Hb, int M, int N,
                                                     int ngb,
                                                     const int* __restrict__ row,
                                                     const int* __restrict__ col,
                                                     int* __restrict__ bcur,
                                                     uint2* __restrict__ stage, int E) {
  __shared__ u16 ABsl[4][5120];  // 40KB: GEMM A/B double-buffer OR pass-A staging
  int b = blockIdx.x;
  if (b < ngb) {
    gemm_body<true, true>(x, W1t, dinv, Hb, M, N, b & 1, b >> 1,
                          *reinterpret_cast<u16(*)[2][5120]>(&ABsl[0]),
                          *reinterpret_cast<u16(*)[2][5120]>(&ABsl[2]));
  } else {
    uint2* pairs = (uint2*)ABsl;                       // 4096 pairs = 32KB
    int* hcnt = (int*)((char*)ABsl + 32768);           // [256]
    int* hscan = hcnt + 256;                           // [256]
    int* hbase = hscan + 256;                          // [256]
    int* lcur = hbase + 256;                           // [256]

    const int tid = threadIdx.x;
    const int blk = b - ngb;
    const int e0 = blk * CHUNK;

    hcnt[tid] = 0;
    __syncthreads();

    int ecol[16], erow[16];
#pragma unroll
    for (int j = 0; j < 16; ++j) {
      int e = e0 + j * 256 + tid;
      if (e < E) {
        ecol[j] = col[e];
        erow[j] = row[e];
        atomicAdd(&hcnt[ecol[j] >> 8], 1);
      } else {
        ecol[j] = -1;
      }
    }
    __syncthreads();

    hscan[tid] = hcnt[tid];
    __syncthreads();
#pragma unroll
    for (int off = 1; off < 256; off <<= 1) {
      int t = (tid >= off) ? hscan[tid - off] : 0;
      __syncthreads();
      hscan[tid] += t;
      __syncthreads();
    }

    lcur[tid] = 0;
    if (hcnt[tid] > 0) hbase[tid] = atomicAdd(&bcur[tid], hcnt[tid]);
    __syncthreads();

#pragma unroll
    for (int j = 0; j < 16; ++j) {
      if (ecol[j] >= 0) {
        int bk = ecol[j] >> 8;
        int p = atomicAdd(&lcur[bk], 1);
        pairs[(hscan[bk] - hcnt[bk]) + p] = make_uint2((unsigned)erow[j], (unsigned)ecol[j]);
      }
    }
    __syncthreads();

    int mtot = hscan[255];
    for (int s = tid; s < mtot; s += 256) {
      uint2 pr = pairs[s];
      int bk = (int)(pr.y >> 8);
      stage[hbase[bk] + (s - (hscan[bk] - hcnt[bk]))] = pr;
    }
  }
}

// pass B: per-bucket counting-sort to exact csr positions, inserting one
// self-loop per node FIRST in its range. low16 = src row index (<= NN < 2^16).
__global__ __launch_bounds__(256) void csr_sort(const uint2* __restrict__ stage,
                                                const int* __restrict__ row_off,
                                                u32* __restrict__ csrp) {
  __shared__ int cur[256];
  __shared__ u32 outb[CAP_B];
  const int b = blockIdx.x;
  const int base_node = b << 8;
  const int nnodes = min(256, NN - base_node);
  const int tid = threadIdx.x;
  const int bstart = row_off[base_node];
  const int bend = row_off[min(base_node + 256, NN)];
  if (tid < nnodes) {
    int c0 = row_off[base_node + tid] - bstart;
    outb[c0] = (u32)(base_node + tid);  // self-loop first
    cur[tid] = c0 + 1;
  }
  __syncthreads();
  const int m = bend - bstart;
  const int mreal = m - nnodes;  // staged (real) edges in this bucket
  for (int i = tid; i < mreal; i += 256) {
    uint2 pr = stage[bstart + i];
    int cl = ((int)pr.y - base_node) & 255;  // defensive
    int p = atomicAdd(&cur[cl], 1);
    u32 val = pr.x & 0xFFFFu;
    if (p < CAP_B) outb[p] = val;
    else if (bstart + p < NET) csrp[bstart + p] = val;  // bounded fallback
  }
  __syncthreads();
  const int mm = min(m, CAP_B);
  for (int i = tid; i < mm; i += 256) csrp[bstart + i] = outb[i];
}

// ---------------- aggregation: planar XCD slices, 8-deep scalar gathers ----------------
// out[v][cg] = dinv[v] * sum_{k in csr(v) incl self} H[slice][src k][c] + bias.
// r9 post-mortem: the MFMA/LDS path was serial-latency-bound (asm "memory"
// clobber forced vmcnt(0)/iter); r7's VALU read was wrong — real limiter was
// MLP (4 gathers in flight ~= 92 outstanding VMEM/CU vs ~225 needed for the
// per-XCD L2 at ~250cy). This kernel: 16 nodes/wave x 4 lanes/node x 8ch
// (16B) per lane; per 8-edge window load the window's csrp words directly
// (2x dwordx4, L1-broadcast across the node's 4 lanes), clamp tail slots to
// the plane zero row (L1-resident -> waste windows are ~free BW-wise), issue
// 8 x 16B gathers batched (8 outstanding), accumulate via v_pk_add_f32
// IN-LANE — no cross-lane reduce, no LDS, no inline asm.
template <int NPL, int OUTC, bool RELU_BF16>
__global__ __launch_bounds__(256) void agg_gather(const u16* __restrict__ h,
                                                  const int* __restrict__ row_off,
                                                  const u32* __restrict__ csrp,
                                                  const float* __restrict__ dinv,
                                                  const float* __restrict__ bias,
                                                  void* __restrict__ outp) {
  const int slice = blockIdx.x % NPL;
  const int wave = threadIdx.x >> 6;
  const int lane = threadIdx.x & 63;
  const int nd = lane >> 2;            // node within wave (0..15)
  const int c = lane & 3;              // 8-ch segment (16B)
  const int v = (blockIdx.x / NPL) * 64 + wave * 16 + nd;
  if (v >= NN) return;                 // divergent tail ok: no barriers below
  const u16* hpl = h + (size_t)slice * CPS;
  const int beg = row_off[v], end = row_off[v + 1];  // >=1 entry (self-loop)
  const int coff = c * 8;

  f32x2 a0 = {}, a1 = {}, a2 = {}, a3 = {};
  for (int p = beg; p < end; p += 8) {
    // window's 8 indices, loaded directly (csrp has +256 dword slack)
    u32x4u cwa = *(const u32x4u*)&csrp[p];
    u32x4u cwb = *(const u32x4u*)&csrp[p + 4];
    unsigned s0 = (p + 0 < end) ? (cwa[0] & 0xFFFFu) : (unsigned)NN;
    unsigned s1 = (p + 1 < end) ? (cwa[1] & 0xFFFFu) : (unsigned)NN;
    unsigned s2 = (p + 2 < end) ? (cwa[2] & 0xFFFFu) : (unsigned)NN;
    unsigned s3 = (p + 3 < end) ? (cwa[3] & 0xFFFFu) : (unsigned)NN;
    unsigned s4 = (p + 4 < end) ? (cwb[0] & 0xFFFFu) : (unsigned)NN;
    unsigned s5 = (p + 5 < end) ? (cwb[1] & 0xFFFFu) : (unsigned)NN;
    unsigned s6 = (p + 6 < end) ? (cwb[2] & 0xFFFFu) : (unsigned)NN;
    unsigned s7 = (p + 7 < end) ? (cwb[3] & 0xFFFFu) : (unsigned)NN;
    // 8 gathers batched -> 8 outstanding VMEM
    u32x4 g0 = *(const u32x4*)&hpl[(size_t)s0 * 32 + coff];
    u32x4 g1 = *(const u32x4*)&hpl[(size_t)s1 * 32 + coff];
    u32x4 g2 = *(const u32x4*)&hpl[(size_t)s2 * 32 + coff];
    u32x4 g3 = *(const u32x4*)&hpl[(size_t)s3 * 32 + coff];
    u32x4 g4 = *(const u32x4*)&hpl[(size_t)s4 * 32 + coff];
    u32x4 g5 = *(const u32x4*)&hpl[(size_t)s5 * 32 + coff];
    u32x4 g6 = *(const u32x4*)&hpl[(size_t)s6 * 32 + coff];
    u32x4 g7 = *(const u32x4*)&hpl[(size_t)s7 * 32 + coff];
#pragma unroll
    for (int q = 0; q < 4; ++q) {
      f32x2 t;
      f32x2 acc = {};
      t[0] = __uint_as_float(g0[q] << 16); t[1] = __uint_as_float(g0[q] & 0xffff0000u); acc += t;
      t[0] = __uint_as_float(g1[q] << 16); t[1] = __uint_as_float(g1[q] & 0xffff0000u); acc += t;
      t[0] = __uint_as_float(g2[q] << 16); t[1] = __uint_as_float(g2[q] & 0xffff0000u); acc += t;
      t[0] = __uint_as_float(g3[q] << 16); t[1] = __uint_as_float(g3[q] & 0xffff0000u); acc += t;
      t[0] = __uint_as_float(g4[q] << 16); t[1] = __uint_as_float(g4[q] & 0xffff0000u); acc += t;
      t[0] = __uint_as_float(g5[q] << 16); t[1] = __uint_as_float(g5[q] & 0xffff0000u); acc += t;
      t[0] = __uint_as_float(g6[q] << 16); t[1] = __uint_as_float(g6[q] & 0xffff0000u); acc += t;
      t[0] = __uint_as_float(g7[q] << 16); t[1] = __uint_as_float(g7[q] & 0xffff0000u); acc += t;
      if (q == 0) a0 += acc;
      else if (q == 1) a1 += acc;
      else if (q == 2) a2 += acc;
      else a3 += acc;
    }
  }
  float aa[8] = {a0[0], a0[1], a1[0], a1[1], a2[0], a2[1], a3[0], a3[1]};
  const int cg = slice * 32 + coff;
  float dv = dinv[v];
  float4 bv0 = *(const float4*)&bias[cg];
  float4 bv1 = *(const float4*)&bias[cg + 4];
  float bb[8] = {bv0.x, bv0.y, bv0.z, bv0.w, bv1.x, bv1.y, bv1.z, bv1.w};
  if constexpr (RELU_BF16) {
    u16* o = (u16*)outp;
    ushort8 ov;
#pragma unroll
    for (int i = 0; i < 8; ++i) ov[i] = (short)f2b(fmaxf(aa[i] * dv + bb[i], 0.f));
    *(ushort8*)&o[(size_t)v * OUTC + cg] = ov;
  } else {
    float* o = (float*)outp;
    float ov[8];
#pragma unroll
    for (int i = 0; i < 8; ++i) ov[i] = aa[i] * dv + bb[i];
    *(float4*)&o[(size_t)v * OUTC + cg] = make_float4(ov[0], ov[1], ov[2], ov[3]);
    *(float4*)&o[(size_t)v * OUTC + cg + 4] = make_float4(ov[4], ov[5], ov[6], ov[7]);
  }
}

// ---------------- launch ----------------

extern "C" void kernel_launch(void* const* d_in, const int* in_sizes, int n_in,
                              void* d_out, int out_size, void* d_ws, size_t ws_size,
                              hipStream_t stream) {
  const float* x = (const float*)d_in[0];
  const int* ei = (const int*)d_in[1];
  const float* W1 = (const float*)d_in[2];
  const float* b1 = (const float*)d_in[3];
  const float* W2 = (const float*)d_in[4];
  const float* b2 = (const float*)d_in[5];
  float* out = (float*)d_out;

  const int* row = ei;
  const int* col = ei + NE;

  const int NB = (NN + 255) / 256;  // 196

  // workspace layout — Hb: 8 planar planes [(NN+1)x32]; H3b: 4 planar planes.
  u16* Hb = (u16*)d_ws;                       // 8*CPS bf16, pre-scaled by dinv[row]
  u16* H2b = Hb + (size_t)(NN + 1) * 256;     // [NN,256] bf16 (standard layout)
  u16* H3b = H2b + (size_t)NN * 256;          // 4*CPS bf16, pre-scaled
  u16* W1t = H3b + (size_t)(NN + 1) * 128;    // [256,256] bf16
  u16* W2t = W1t + 256 * 256;                 // [128,256] bf16
  int* cnt = (int*)(W2t + 128 * 256);         // [NN]
  int* row_off = cnt + NN;                    // [NN+4] (padded)
  int* bcur = row_off + NN + 4;               // [256] per-bucket stage cursors
  float* dinv = (float*)(bcur + 256);         // [NN]
  int* bsum = (int*)(dinv + NN);              // [200]
  int* boff = bsum + 200;                     // [200]
  u32* csrp = (u32*)(boff + 200);             // [NET+256] src indices (+slack for window overreads)
  // stage overlays H3b (disjoint lifetimes); H3 zero rows re-seeded in gemm2.
  uint2* stage = (uint2*)H3b;                 // [NE] (row,col) pairs

  convw_zero<<<256 + NB + 1, 256, 0, stream>>>(W1, W2, W1t, W2t, cnt, Hb, NB);
  hist_kernel<<<(NE + 255) / 256, 256, 0, stream>>>(col, cnt, NE);
  scan1_kernel<<<NB, 256, 0, stream>>>(cnt, bsum, NN);
  scan2_kernel<<<1, 256, 0, stream>>>(bsum, boff, row_off, NB, NN);
  scan3_kernel<<<NB, 256, 0, stream>>>(cnt, boff, row_off, bcur, dinv, NN);

  // fused: GEMM1 (planar Hb = dinv * (x@W1), bf16) concurrent with pass-A scatter
  {
    const int ngb = (HID_C / 128) * ((NN + 127) / 128);  // 782
    gemm1_scatter<<<ngb + NPA, 256, 0, stream>>>(x, W1t, dinv, Hb, NN, HID_C, ngb,
                                                 row, col, bcur, stage, NE);
  }
  csr_sort<<<NBUCK, 256, 0, stream>>>(stage, row_off, csrp);

  const int NGB = (NN + 63) / 64;  // 782 blocks of 64 nodes
  // agg1: 8 planes x 32 ch, plane==XCD via blockIdx%8; out = H2b [NN,256] bf16+relu
  agg_gather<8, 256, true><<<NGB * 8, 256, 0, stream>>>(
      Hb, row_off, csrp, dinv, b1, H2b);

  {
    dim3 grid(OUT_C / 128, (NN + 127) / 128);
    gemm_mfma<false, true><<<grid, 256, 0, stream>>>(H2b, W2t, dinv, H3b, NN, OUT_C, H3b);
  }

  // agg2: 4 planes x 32 ch; out = final f32 [NN,128]
  agg_gather<4, 128, false><<<NGB * 4, 256, 0, stream>>>(
      H3b, row_off, csrp, dinv, b2, out);
}

// Round 11
// 262.083 us; speedup vs baseline: 1.2545x; 1.0231x over previous
//
#include <hip/hip_runtime.h>

#define NN 50000
#define NE 800000
#define IN_C 256
#define HID_C 256
#define OUT_C 128

#define NETP (NE + 8 * NN)  // padded csr capacity: sum round_up(deg+1,8) <= NE+8*NN
#define NBUCK 196   // ceil(NN/256) buckets of 256 nodes (by col)
#define CHUNK 4096  // edges per pass-A block
#define NPA 196     // ceil(NE/CHUNK)
#define CAP_B 6400  // pass-B LDS capacity in slots (padded bucket mean ~5350, sigma ~56)

typedef unsigned short u16;
typedef unsigned int u32;
typedef __attribute__((ext_vector_type(8))) short short8;
typedef __attribute__((ext_vector_type(8))) unsigned short ushort8;
typedef __attribute__((ext_vector_type(4))) float f32x4;
typedef __attribute__((ext_vector_type(2))) float f32x2;
typedef __attribute__((ext_vector_type(4))) unsigned u32x4;

// planar plane stride (u16 units): 32 ch x (NN+1) rows, zero row at index NN
#define CPS ((size_t)(NN + 1) * 32)

__device__ __forceinline__ u16 f2b(float f) {
  unsigned int u = __float_as_uint(f);
  return (u16)((u + 0x7FFFu + ((u >> 16) & 1u)) >> 16);  // RNE
}
__device__ __forceinline__ float b2f(u16 s) {
  return __uint_as_float(((unsigned int)s) << 16);
}

// ---------------- fused: weight convert+transpose, cnt init(=1 self), Hb zero rows ----------------

__global__ __launch_bounds__(256) void convw_zero(const float* __restrict__ W1,
                                                  const float* __restrict__ W2,
                                                  u16* __restrict__ W1t,
                                                  u16* __restrict__ W2t,
                                                  int* __restrict__ cnt,
                                                  u16* __restrict__ Hb,
                                                  int nzb) {
  int b = blockIdx.x;
  if (b < 256) {
    int id = b * 256 + threadIdx.x;
    if (id < 256 * 256) {
      int n = id >> 8, k = id & 255;
      W1t[id] = f2b(W1[k * 256 + n]);
    }
    if (id < 128 * 256) {
      int n = id >> 8, k = id & 255;
      W2t[id] = f2b(W2[k * 128 + n]);
    }
  } else if (b < 256 + nzb) {
    int i = (b - 256) * 256 + threadIdx.x;
    if (i < NN) cnt[i] = 1;  // self-loop included in CSR
  } else {
    // zero row at tail of each of the 8 Hb planes (absorbs pad-slot gathers)
    int t = threadIdx.x;  // 256 threads = 8 planes x 32 ch
    Hb[(size_t)(t >> 5) * CPS + (size_t)NN * 32 + (t & 31)] = 0;
  }
}

// ---------------- CSR build ----------------

__global__ __launch_bounds__(256) void hist_kernel(const int* __restrict__ col,
                                                   int* __restrict__ cnt, int E) {
  int e = blockIdx.x * blockDim.x + threadIdx.x;
  if (e < E) atomicAdd(&cnt[col[e]], 1);
}

// scan over PADDED per-node sizes: pad(v) = round_up(v,8)
__global__ __launch_bounds__(256) void scan1_kernel(const int* __restrict__ cnt,
                                                    int* __restrict__ bsum, int n) {
  __shared__ int ws[4];
  int i = blockIdx.x * 256 + threadIdx.x;
  int lane = threadIdx.x & 63, wid = threadIdx.x >> 6;
  int v = (i < n) ? ((cnt[i] + 7) & ~7) : 0;
#pragma unroll
  for (int off = 32; off > 0; off >>= 1) v += __shfl_down(v, off, 64);
  if (lane == 0) ws[wid] = v;
  __syncthreads();
  if (threadIdx.x == 0) bsum[blockIdx.x] = ws[0] + ws[1] + ws[2] + ws[3];
}

__global__ __launch_bounds__(256) void scan2_kernel(const int* __restrict__ bsum,
                                                    int* __restrict__ boff,
                                                    int* __restrict__ row_off,
                                                    int nb, int n) {
  __shared__ int wsum[4], wpre[5];
  int lane = threadIdx.x & 63, wid = threadIdx.x >> 6;
  int v = (threadIdx.x < nb) ? bsum[threadIdx.x] : 0;
  int s = v;
#pragma unroll
  for (int off = 1; off < 64; off <<= 1) {
    int t = __shfl_up(s, off, 64);
    if (lane >= off) s += t;
  }
  if (lane == 63) wsum[wid] = s;
  __syncthreads();
  if (threadIdx.x == 0) {
    int acc = 0;
#pragma unroll
    for (int w = 0; w < 4; ++w) { wpre[w] = acc; acc += wsum[w]; }
    wpre[4] = acc;
  }
  __syncthreads();
  if (threadIdx.x < nb) boff[threadIdx.x] = wpre[wid] + (s - v);
  if (threadIdx.x == 0) row_off[n] = wpre[4];
}

// scan3: padded offsets into row_off; bcur[b] = row_off[b*256]; dinv from RAW count
__global__ __launch_bounds__(256) void scan3_kernel(const int* __restrict__ cnt,
                                                    const int* __restrict__ boff,
                                                    int* __restrict__ row_off,
                                                    int* __restrict__ bcur,
                                                    float* __restrict__ dinv, int n) {
  __shared__ int wsum[4], wpre[4];
  int i = blockIdx.x * 256 + threadIdx.x;
  int lane = threadIdx.x & 63, wid = threadIdx.x >> 6;
  int vr = (i < n) ? cnt[i] : 0;       // raw deg+1
  int v = (vr + 7) & ~7;               // padded
  int s = v;
#pragma unroll
  for (int off = 1; off < 64; off <<= 1) {
    int t = __shfl_up(s, off, 64);
    if (lane >= off) s += t;
  }
  if (lane == 63) wsum[wid] = s;
  __syncthreads();
  if (threadIdx.x == 0) {
    int acc = 0;
#pragma unroll
    for (int w = 0; w < 4; ++w) { wpre[w] = acc; acc += wsum[w]; }
  }
  __syncthreads();
  if (i < n) {
    int off = boff[blockIdx.x] + wpre[wid] + (s - v);
    row_off[i] = off;
    if ((i & 255) == 0) bcur[i >> 8] = off;
    dinv[i] = rsqrtf((float)vr);
  }
}

// ---------------- MFMA GEMM body (shared by plain and fused kernels) ----------------
// PLANAR_C: C write remapped to [gc>>5][gr][gc&31] planes of stride CPS.

template <bool A_IS_F32, bool PLANAR_C>
__device__ __forceinline__ void gemm_body(const void* __restrict__ Ap,
                                          const u16* __restrict__ Bt,
                                          const float* __restrict__ dscale,
                                          u16* __restrict__ C, int M, int N,
                                          int bx, int by,
                                          u16 (&Asl)[2][5120], u16 (&Bsl)[2][5120]) {
  const int tid = threadIdx.x;
  const int row0 = by * 128;
  const int col0 = bx * 128;

  f32x4 acc[4][4] = {};

  const int seg = tid & 7;
  const int rb = tid >> 3;
  const int wave = tid >> 6, lane = tid & 63;
  const int wm = wave >> 1, wn = wave & 1;
  const int qr = lane & 15, quad = lane >> 4;

  float4 aF[4];
  ushort4 aU[4];
  ushort4 bR[4];

  auto load_tiles = [&](int k0) {
    if constexpr (A_IS_F32) {
      const float* A = (const float*)Ap;
#pragma unroll
      for (int i = 0; i < 4; ++i) {
        int gr = row0 + rb + i * 32;
        aF[i] = (gr < M) ? *(const float4*)&A[(size_t)gr * 256 + k0 + seg * 4]
                         : make_float4(0.f, 0.f, 0.f, 0.f);
      }
    } else {
      const u16* A = (const u16*)Ap;
#pragma unroll
      for (int i = 0; i < 4; ++i) {
        int gr = row0 + rb + i * 32;
        aU[i] = (gr < M) ? *(const ushort4*)&A[(size_t)gr * 256 + k0 + seg * 4]
                         : make_ushort4(0, 0, 0, 0);
      }
    }
#pragma unroll
    for (int i = 0; i < 4; ++i) {
      int n = rb + i * 32;
      bR[i] = *(const ushort4*)&Bt[(size_t)(col0 + n) * 256 + k0 + seg * 4];
    }
  };

  auto write_lds = [&](int buf) {
#pragma unroll
    for (int i = 0; i < 4; ++i) {
      int r = rb + i * 32;
      ushort4 u;
      if constexpr (A_IS_F32) {
        u.x = f2b(aF[i].x); u.y = f2b(aF[i].y);
        u.z = f2b(aF[i].z); u.w = f2b(aF[i].w);
      } else {
        u = aU[i];
      }
      *(ushort4*)&Asl[buf][r * 40 + seg * 4] = u;
      *(ushort4*)&Bsl[buf][r * 40 + seg * 4] = bR[i];
    }
  };

  load_tiles(0);
  write_lds(0);
  __syncthreads();

#pragma unroll
  for (int it = 0; it < 8; ++it) {
    const int cur = it & 1;
    if (it < 7) load_tiles((it + 1) * 32);

    short8 afr[4], bfr[4];
#pragma unroll
    for (int mt = 0; mt < 4; ++mt)
      afr[mt] = *(const short8*)&Asl[cur][(wm * 64 + mt * 16 + qr) * 40 + quad * 8];
#pragma unroll
    for (int nt = 0; nt < 4; ++nt)
      bfr[nt] = *(const short8*)&Bsl[cur][(wn * 64 + nt * 16 + qr) * 40 + quad * 8];
#pragma unroll
    for (int mt = 0; mt < 4; ++mt)
#pragma unroll
      for (int nt = 0; nt < 4; ++nt)
        acc[mt][nt] = __builtin_amdgcn_mfma_f32_16x16x32_bf16(afr[mt], bfr[nt], acc[mt][nt], 0, 0, 0);

    if (it < 7) {
      write_lds(1 - cur);
      __syncthreads();
    }
  }

#pragma unroll
  for (int mt = 0; mt < 4; ++mt) {
#pragma unroll
    for (int i = 0; i < 4; ++i) {
      int gr = row0 + wm * 64 + mt * 16 + quad * 4 + i;
      if (gr < M) {
        float sc = dscale[gr];
#pragma unroll
        for (int nt = 0; nt < 4; ++nt) {
          int gc = col0 + wn * 64 + nt * 16 + qr;
          u16 val = f2b(acc[mt][nt][i] * sc);
          if constexpr (PLANAR_C)
            C[(size_t)(gc >> 5) * CPS + (size_t)gr * 32 + (gc & 31)] = val;
          else
            C[(size_t)gr * N + gc] = val;
        }
      }
    }
  }
}

// plain GEMM kernel (layer 2): planar C out; block (0,0) seeds the 4 H3 plane
// zero rows (must happen after csr_sort consumed the stage overlay).
template <bool A_IS_F32, bool PLANAR_C>
__global__ __launch_bounds__(256) void gemm_mfma(const void* __restrict__ Ap,
                                                 const u16* __restrict__ Bt,
                                                 const float* __restrict__ dscale,
                                                 u16* __restrict__ C, int M, int N,
                                                 u16* __restrict__ zrow) {
  if (zrow != nullptr && blockIdx.x == 0 && blockIdx.y == 0 && threadIdx.x < 128) {
    int t = threadIdx.x;  // 4 planes x 32 ch
    zrow[(size_t)(t >> 5) * CPS + (size_t)NN * 32 + (t & 31)] = 0;
  }
  __shared__ u16 Asl[2][5120];
  __shared__ u16 Bsl[2][5120];
  gemm_body<A_IS_F32, PLANAR_C>(Ap, Bt, dscale, C, M, N, blockIdx.x, blockIdx.y, Asl, Bsl);
}

// fused: GEMM1 (blocks [0,ngb), planar Hb out) + pass-A bucket scatter
__global__ __launch_bounds__(256) void gemm1_scatter(const float* __restrict__ x,
                                                     const u16* __restrict__ W1t,
                                                     const float* __restrict__ dinv,
                                                     u16* __restrict__ Hb, int M, int N,
                                                     int ngb,
                                                     const int* __restrict__ row,
                                                     const int* __restrict__ col,
                                                     int* __restrict__ bcur,
                                                     uint2* __restrict__ stage, int E) {
  __shared__ u16 ABsl[4][5120];  // 40KB: GEMM A/B double-buffer OR pass-A staging
  int b = blockIdx.x;
  if (b < ngb) {
    gemm_body<true, true>(x, W1t, dinv, Hb, M, N, b & 1, b >> 1,
                          *reinterpret_cast<u16(*)[2][5120]>(&ABsl[0]),
                          *reinterpret_cast<u16(*)[2][5120]>(&ABsl[2]));
  } else {
    uint2* pairs = (uint2*)ABsl;                       // 4096 pairs = 32KB
    int* hcnt = (int*)((char*)ABsl + 32768);           // [256]
    int* hscan = hcnt + 256;                           // [256]
    int* hbase = hscan + 256;                          // [256]
    int* lcur = hbase + 256;                           // [256]

    const int tid = threadIdx.x;
    const int blk = b - ngb;
    const int e0 = blk * CHUNK;

    hcnt[tid] = 0;
    __syncthreads();

    int ecol[16], erow[16];
#pragma unroll
    for (int j = 0; j < 16; ++j) {
      int e = e0 + j * 256 + tid;
      if (e < E) {
        ecol[j] = col[e];
        erow[j] = row[e];
        atomicAdd(&hcnt[ecol[j] >> 8], 1);
      } else {
        ecol[j] = -1;
      }
    }
    __syncthreads();

    hscan[tid] = hcnt[tid];
    __syncthreads();
#pragma unroll
    for (int off = 1; off < 256; off <<= 1) {
      int t = (tid >= off) ? hscan[tid - off] : 0;
      __syncthreads();
      hscan[tid] += t;
      __syncthreads();
    }

    lcur[tid] = 0;
    if (hcnt[tid] > 0) hbase[tid] = atomicAdd(&bcur[tid], hcnt[tid]);
    __syncthreads();

#pragma unroll
    for (int j = 0; j < 16; ++j) {
      if (ecol[j] >= 0) {
        int bk = ecol[j] >> 8;
        int p = atomicAdd(&lcur[bk], 1);
        pairs[(hscan[bk] - hcnt[bk]) + p] = make_uint2((unsigned)erow[j], (unsigned)ecol[j]);
      }
    }
    __syncthreads();

    int mtot = hscan[255];
    for (int s = tid; s < mtot; s += 256) {
      uint2 pr = pairs[s];
      int bk = (int)(pr.y >> 8);
      stage[hbase[bk] + (s - (hscan[bk] - hcnt[bk]))] = pr;
    }
  }
}

// pass B: per-bucket counting-sort to exact (padded) csr positions, u16 output.
// Self-loop first per node; ALL pad slots pre-filled with NN (zero row).
// mreal recovered from bcur (post-scatter cursor) since bucket size is padded.
__global__ __launch_bounds__(256) void csr_sort(const uint2* __restrict__ stage,
                                                const int* __restrict__ row_off,
                                                const int* __restrict__ bcur,
                                                u16* __restrict__ csrp) {
  __shared__ int cur[256];
  __shared__ u16 outb[CAP_B];
  const int b = blockIdx.x;
  const int base_node = b << 8;
  const int nnodes = min(256, NN - base_node);
  const int tid = threadIdx.x;
  const int bstart = row_off[base_node];
  const int bend = row_off[min(base_node + 256, NN)];
  const int m = bend - bstart;          // padded bucket size
  const int mm = min(m, CAP_B);
  for (int i = tid; i < mm; i += 256) outb[i] = (u16)NN;     // pad fill (LDS)
  for (int i = CAP_B + tid; i < m; i += 256) csrp[bstart + i] = (u16)NN;  // overflow pad fill
  __syncthreads();
  if (tid < nnodes) {
    int c0 = row_off[base_node + tid] - bstart;
    outb[c0] = (u16)(base_node + tid);  // self-loop first
    cur[tid] = c0 + 1;
  }
  __syncthreads();
  const int mreal = bcur[b] - bstart - 0;  // staged real edges (bcur advanced past bstart)
  for (int i = tid; i < mreal; i += 256) {
    uint2 pr = stage[bstart + i];
    int cl = ((int)pr.y - base_node) & 255;  // defensive
    int p = atomicAdd(&cur[cl], 1);
    if (p < CAP_B) outb[p] = (u16)pr.x;
    else if (bstart + p < NETP) csrp[bstart + p] = (u16)pr.x;  // bounded fallback
  }
  __syncthreads();
  for (int i = tid; i < mm; i += 256) csrp[bstart + i] = outb[i];
}

// ---------------- aggregation: planar XCD slices, prefetched 8-slot windows ----------------
// out[v][cg] = dinv[v] * sum_{slots of v incl self & pads} H[slice][idx][c] + bias.
// r10 post-mortem: csrp load sat INSIDE the per-window chain (~500cy serial) and
// csrp u32 stream (27MB across XCDs) thrashed L2 (FETCH 60MB). This round:
//  - csrp is u16 with every node's range padded to 8 slots (pad idx = NN ->
//    zero row, L1-resident): window load = one aligned 16B ushort8, and the
//    8 per-slot range compares are GONE.
//  - next window's csrp is prefetched unconditionally (slack-backed overread;
//    values possibly garbage are never consumed, addresses always mapped) ->
//    csrp latency fully hidden under current window's gathers+unpack.
//  - 8 gathers batched, in-lane v_pk_add_f32 accumulate, no LDS, no asm.
template <int NPL, int OUTC, bool RELU_BF16>
__global__ __launch_bounds__(256) void agg_gather(const u16* __restrict__ h,
                                                  const int* __restrict__ row_off,
                                                  const u16* __restrict__ csrp,
                                                  const float* __restrict__ dinv,
                                                  const float* __restrict__ bias,
                                                  void* __restrict__ outp) {
  const int slice = blockIdx.x % NPL;
  const int wave = threadIdx.x >> 6;
  const int lane = threadIdx.x & 63;
  const int nd = lane >> 2;            // node within wave (0..15)
  const int c = lane & 3;              // 8-ch segment (16B)
  const int v = (blockIdx.x / NPL) * 64 + wave * 16 + nd;
  if (v >= NN) return;                 // divergent tail ok: no barriers below
  const u16* hpl = h + (size_t)slice * CPS;
  const int beg = row_off[v], end = row_off[v + 1];  // 8-aligned, >=8 slots
  const int coff = c * 8;

  f32x2 a0 = {}, a1 = {}, a2 = {}, a3 = {};
  ushort8 cwA = *(const ushort8*)&csrp[beg];
  for (int p = beg; p < end; p += 8) {
    ushort8 cwB = *(const ushort8*)&csrp[p + 8];  // prefetch next window (slack-backed)
    u32x4 g0 = *(const u32x4*)&hpl[(size_t)cwA[0] * 32 + coff];
    u32x4 g1 = *(const u32x4*)&hpl[(size_t)cwA[1] * 32 + coff];
    u32x4 g2 = *(const u32x4*)&hpl[(size_t)cwA[2] * 32 + coff];
    u32x4 g3 = *(const u32x4*)&hpl[(size_t)cwA[3] * 32 + coff];
    u32x4 g4 = *(const u32x4*)&hpl[(size_t)cwA[4] * 32 + coff];
    u32x4 g5 = *(const u32x4*)&hpl[(size_t)cwA[5] * 32 + coff];
    u32x4 g6 = *(const u32x4*)&hpl[(size_t)cwA[6] * 32 + coff];
    u32x4 g7 = *(const u32x4*)&hpl[(size_t)cwA[7] * 32 + coff];
#pragma unroll
    for (int q = 0; q < 4; ++q) {
      f32x2 t;
      f32x2 acc = {};
      t[0] = __uint_as_float(g0[q] << 16); t[1] = __uint_as_float(g0[q] & 0xffff0000u); acc += t;
      t[0] = __uint_as_float(g1[q] << 16); t[1] = __uint_as_float(g1[q] & 0xffff0000u); acc += t;
      t[0] = __uint_as_float(g2[q] << 16); t[1] = __uint_as_float(g2[q] & 0xffff0000u); acc += t;
      t[0] = __uint_as_float(g3[q] << 16); t[1] = __uint_as_float(g3[q] & 0xffff0000u); acc += t;
      t[0] = __uint_as_float(g4[q] << 16); t[1] = __uint_as_float(g4[q] & 0xffff0000u); acc += t;
      t[0] = __uint_as_float(g5[q] << 16); t[1] = __uint_as_float(g5[q] & 0xffff0000u); acc += t;
      t[0] = __uint_as_float(g6[q] << 16); t[1] = __uint_as_float(g6[q] & 0xffff0000u); acc += t;
      t[0] = __uint_as_float(g7[q] << 16); t[1] = __uint_as_float(g7[q] & 0xffff0000u); acc += t;
      if (q == 0) a0 += acc;
      else if (q == 1) a1 += acc;
      else if (q == 2) a2 += acc;
      else a3 += acc;
    }
    cwA = cwB;
  }
  float aa[8] = {a0[0], a0[1], a1[0], a1[1], a2[0], a2[1], a3[0], a3[1]};
  const int cg = slice * 32 + coff;
  float dv = dinv[v];
  float4 bv0 = *(const float4*)&bias[cg];
  float4 bv1 = *(const float4*)&bias[cg + 4];
  float bb[8] = {bv0.x, bv0.y, bv0.z, bv0.w, bv1.x, bv1.y, bv1.z, bv1.w};
  if constexpr (RELU_BF16) {
    u16* o = (u16*)outp;
    ushort8 ov;
#pragma unroll
    for (int i = 0; i < 8; ++i) ov[i] = (short)f2b(fmaxf(aa[i] * dv + bb[i], 0.f));
    *(ushort8*)&o[(size_t)v * OUTC + cg] = ov;
  } else {
    float* o = (float*)outp;
    float ov[8];
#pragma unroll
    for (int i = 0; i < 8; ++i) ov[i] = aa[i] * dv + bb[i];
    *(float4*)&o[(size_t)v * OUTC + cg] = make_float4(ov[0], ov[1], ov[2], ov[3]);
    *(float4*)&o[(size_t)v * OUTC + cg + 4] = make_float4(ov[4], ov[5], ov[6], ov[7]);
  }
}

// ---------------- launch ----------------

extern "C" void kernel_launch(void* const* d_in, const int* in_sizes, int n_in,
                              void* d_out, int out_size, void* d_ws, size_t ws_size,
                              hipStream_t stream) {
  const float* x = (const float*)d_in[0];
  const int* ei = (const int*)d_in[1];
  const float* W1 = (const float*)d_in[2];
  const float* b1 = (const float*)d_in[3];
  const float* W2 = (const float*)d_in[4];
  const float* b2 = (const float*)d_in[5];
  float* out = (float*)d_out;

  const int* row = ei;
  const int* col = ei + NE;

  const int NB = (NN + 255) / 256;  // 196

  // workspace layout — Hb: 8 planar planes [(NN+1)x32]; H3b: 4 planar planes.
  u16* Hb = (u16*)d_ws;                       // 8*CPS bf16, pre-scaled by dinv[row]
  u16* H2b = Hb + (size_t)(NN + 1) * 256;     // [NN,256] bf16 (standard layout)
  u16* H3b = H2b + (size_t)NN * 256;          // 4*CPS bf16, pre-scaled
  u16* W1t = H3b + (size_t)(NN + 1) * 128;    // [256,256] bf16
  u16* W2t = W1t + 256 * 256;                 // [128,256] bf16
  int* cnt = (int*)(W2t + 128 * 256);         // [NN]
  int* row_off = cnt + NN;                    // [NN+4] (padded)
  int* bcur = row_off + NN + 4;               // [256] per-bucket stage cursors
  float* dinv = (float*)(bcur + 256);         // [NN]
  int* bsum = (int*)(dinv + NN);              // [200]
  int* boff = bsum + 200;                     // [200]
  u16* csrp = (u16*)(boff + 200);             // [NETP+64] padded u16 indices
  // stage overlays H3b (padded coords, max 1.2M pairs = 9.6MB <= 12.8MB);
  // H3 zero rows re-seeded in gemm2 (after csr_sort consumed the overlay).
  uint2* stage = (uint2*)H3b;                 // [<=NETP] (row,col) pairs

  convw_zero<<<256 + NB + 1, 256, 0, stream>>>(W1, W2, W1t, W2t, cnt, Hb, NB);
  hist_kernel<<<(NE + 255) / 256, 256, 0, stream>>>(col, cnt, NE);
  scan1_kernel<<<NB, 256, 0, stream>>>(cnt, bsum, NN);
  scan2_kernel<<<1, 256, 0, stream>>>(bsum, boff, row_off, NB, NN);
  scan3_kernel<<<NB, 256, 0, stream>>>(cnt, boff, row_off, bcur, dinv, NN);

  // fused: GEMM1 (planar Hb = dinv * (x@W1), bf16) concurrent with pass-A scatter
  {
    const int ngb = (HID_C / 128) * ((NN + 127) / 128);  // 782
    gemm1_scatter<<<ngb + NPA, 256, 0, stream>>>(x, W1t, dinv, Hb, NN, HID_C, ngb,
                                                 row, col, bcur, stage, NE);
  }
  csr_sort<<<NBUCK, 256, 0, stream>>>(stage, row_off, bcur, csrp);

  const int NGB = (NN + 63) / 64;  // 782 blocks of 64 nodes
  // agg1: 8 planes x 32 ch, plane==XCD via blockIdx%8; out = H2b [NN,256] bf16+relu
  agg_gather<8, 256, true><<<NGB * 8, 256, 0, stream>>>(
      Hb, row_off, csrp, dinv, b1, H2b);

  {
    dim3 grid(OUT_C / 128, (NN + 127) / 128);
    gemm_mfma<false, true><<<grid, 256, 0, stream>>>(H2b, W2t, dinv, H3b, NN, OUT_C, H3b);
  }

  // agg2: 4 planes x 32 ch; out = final f32 [NN,128]
  agg_gather<4, 128, false><<<NGB * 4, 256, 0, stream>>>(
      H3b, row_off, csrp, dinv, b2, out);
}